// Round 1
// 655.911 us; speedup vs baseline: 1.0096x; 1.0096x over previous
//
#include <hip/hip_runtime.h>
#include <stdint.h>

typedef float f32x4 __attribute__((ext_vector_type(4)));
typedef short bf16x8 __attribute__((ext_vector_type(8)));
typedef _Float16 f16x8 __attribute__((ext_vector_type(8)));

#define AS1 __attribute__((address_space(1)))
#define AS3 __attribute__((address_space(3)))

#define NB 32
#define NS 2048
#define ND 1024
#define NU 1024
#define NM (NB * NS)  // 65536 rows

// async 16B global->LDS (gfx950). LDS dest = wave-uniform base + lane*16.
__device__ __forceinline__ void glds16(const void* g, void* l) {
  __builtin_amdgcn_global_load_lds((const AS1 uint32_t*)g, (AS3 uint32_t*)l, 16, 0, 0);
}

__device__ __forceinline__ unsigned short bf16_rne(float f) {
  uint32_t u = __float_as_uint(f);
  u += 0x7fffu + ((u >> 16) & 1u);
  return (unsigned short)(u >> 16);
}

// two fp32 -> packed fp16 pair (RNE via v_cvt_f16_f32)
__device__ __forceinline__ uint32_t h2pack(float lo, float hi) {
  union { _Float16 h[2]; uint32_t u; } p;
  p.h[0] = (_Float16)lo;
  p.h[1] = (_Float16)hi;
  return p.u;
}

// (bf16_trunc(hi) << 16) | bf16_trunc(lo) in one v_perm_b32
__device__ __forceinline__ uint32_t pack_bf16_trunc(float lo, float hi) {
  return __builtin_amdgcn_perm(__float_as_uint(hi), __float_as_uint(lo), 0x07060302u);
}

__device__ __forceinline__ float fast_tanh(float x) {
  float e = __expf(2.0f * x);
  return 1.0f - 2.0f / (e + 1.0f);
}

// ---------------- values fp32 -> fp16 (RNE), 67.1M elems ------------------------
__global__ __launch_bounds__(256) void k_cvt(const float* __restrict__ values,
                                             _Float16* __restrict__ values_h) {
  const size_t gid = (size_t)blockIdx.x * 256 + threadIdx.x;
#pragma unroll 2
  for (int it = 0; it < 8; ++it) {
    const size_t e0 = gid * 8 + (size_t)it * 8388608;  // 1,048,576 thr * 8 elems
    f32x4 v0 = *(const f32x4*)(values + e0);
    f32x4 v1 = *(const f32x4*)(values + e0 + 4);
    uint4 o;
    o.x = h2pack(v0.x, v0.y);
    o.y = h2pack(v0.z, v0.w);
    o.z = h2pack(v1.x, v1.y);
    o.w = h2pack(v1.z, v1.w);
    *(uint4*)(values_h + e0) = o;
  }
}

// ---------------- W1[k][u] fp32 -> W1T[u][k] fp16 (RNE) -------------------------
__global__ __launch_bounds__(256) void k_w1t_h(const float* __restrict__ W1,
                                               _Float16* __restrict__ W1T) {
  __shared__ float t[64][65];
  const int n0 = blockIdx.x * 64, k0 = blockIdx.y * 64;
  const int tid = threadIdx.x;
  {
    const int r = tid >> 4, c4 = (tid & 15) << 2;
#pragma unroll
    for (int i = 0; i < 4; ++i) {
      f32x4 v = *(const f32x4*)(W1 + (size_t)(k0 + r + i * 16) * NU + n0 + c4);
      t[r + i * 16][c4 + 0] = v.x;
      t[r + i * 16][c4 + 1] = v.y;
      t[r + i * 16][c4 + 2] = v.z;
      t[r + i * 16][c4 + 3] = v.w;
    }
  }
  __syncthreads();
  const int rr = tid >> 2, cc = tid & 3;
  uint32_t o[8];
#pragma unroll
  for (int p = 0; p < 8; ++p)
    o[p] = h2pack(t[cc * 16 + 2 * p + 0][rr], t[cc * 16 + 2 * p + 1][rr]);
  _Float16* dst = W1T + (size_t)(n0 + rr) * ND + k0 + cc * 16;
  *(uint4*)(dst + 0) = make_uint4(o[0], o[1], o[2], o[3]);
  *(uint4*)(dst + 8) = make_uint4(o[4], o[5], o[6], o[7]);
}

// ---------------- W1 -> bf16 W1T (fallback path) --------------------------------
__global__ __launch_bounds__(256) void k_w1t(const float* __restrict__ W1,
                                             unsigned short* __restrict__ W1T) {
  __shared__ float t[64][65];
  const int n0 = blockIdx.x * 64, k0 = blockIdx.y * 64;
  const int tid = threadIdx.x;
  {
    const int r = tid >> 4, c4 = (tid & 15) << 2;
#pragma unroll
    for (int i = 0; i < 4; ++i) {
      f32x4 v = *(const f32x4*)(W1 + (size_t)(k0 + r + i * 16) * NU + n0 + c4);
      t[r + i * 16][c4 + 0] = v.x;
      t[r + i * 16][c4 + 1] = v.y;
      t[r + i * 16][c4 + 2] = v.z;
      t[r + i * 16][c4 + 3] = v.w;
    }
  }
  __syncthreads();
  const int rr = tid >> 2, cc = tid & 3;
  uint32_t o[8];
#pragma unroll
  for (int p = 0; p < 8; ++p) {
    float f0 = t[cc * 16 + 2 * p + 0][rr];
    float f1 = t[cc * 16 + 2 * p + 1][rr];
    o[p] = (uint32_t)bf16_rne(f0) | ((uint32_t)bf16_rne(f1) << 16);
  }
  unsigned short* dst = W1T + (size_t)(n0 + rr) * ND + k0 + cc * 16;
  *(uint4*)(dst + 0) = make_uint4(o[0], o[1], o[2], o[3]);
  *(uint4*)(dst + 8) = make_uint4(o[4], o[5], o[6], o[7]);
}

// ---------------- pq partials over k-chunks (f32x4 ILP) -------------------------
__global__ __launch_bounds__(256) void k_pq(const float* __restrict__ query,
                                            const float* __restrict__ W2,
                                            float* __restrict__ pq_part) {
  const int kc = blockIdx.x, b = blockIdx.y;
  const int u4 = threadIdx.x * 4;
  const float* q = query + b * ND + kc * 256;  // wave-uniform -> s_load
  f32x4 a0 = (f32x4){0.f, 0.f, 0.f, 0.f}, a1 = a0;
  const float* w = W2 + (size_t)kc * 256 * NU + u4;
  for (int k = 0; k < 256; k += 8) {
#pragma unroll
    for (int j = 0; j < 8; j += 2) {
      a0 += q[k + j + 0] * *(const f32x4*)(w + (size_t)(k + j + 0) * NU);
      a1 += q[k + j + 1] * *(const f32x4*)(w + (size_t)(k + j + 1) * NU);
    }
  }
  *(f32x4*)(pq_part + (size_t)(kc * NB + b) * NU + u4) = a0 + a1;
}

__global__ __launch_bounds__(256) void k_pq_red(const float* __restrict__ pq_part,
                                                const float* __restrict__ b1,
                                                const float* __restrict__ b2,
                                                float* __restrict__ pq) {
  const int b = blockIdx.x, u4 = threadIdx.x * 4;
  f32x4 acc = *(const f32x4*)(b1 + u4) + *(const f32x4*)(b2 + u4);
#pragma unroll
  for (int kc = 0; kc < 4; ++kc)
    acc += *(const f32x4*)(pq_part + (size_t)(kc * NB + b) * NU + u4);
  *(f32x4*)(pq + (size_t)b * NU + u4) = acc;
}

// ---------------- fused GEMM (values_h @ W1T_h) + tanh·V score ------------------
// 256x256 tile, BK=64, 8 waves (2M x 4N), 128 KiB LDS dbuf, 8-phase schedule with
// counted vmcnt (T3+T4), st-style XOR swizzle (T2), setprio around MFMA (T5).
//
// LDS map: buf p (p = K-tile parity) at p*65536; A [256 rows][64k] at +0 (32 KiB,
// 128 B rows), B (=W1T rows) at +32768. Swizzle: phys col16 = logical ^ (row&7),
// applied on BOTH sides (pre-swizzled glds16 *source* column + swizzled ds_read).
//
// Stage slots (1 half-tile = 16 KiB = 2 glds16/wave per phase), iteration I
// computes tiles e=2I (buf0, ph1-4) and o=2I+1 (buf1, ph5-8):
//   ph1: B.h0(o)->buf1   ph2: B.h1(o)->buf1   ph3: A.h0(2I+2)->buf0
//   ph4: A.h1(2I+2)      ph5: B.h0(2I+2)      ph6: B.h1(2I+2)
//   ph7: A.h0(2I+3)->buf1 ph8: A.h1(2I+3)
// WAR: every phase's ds_reads complete before its post-MFMA barrier (mid-barrier +
// lgkmcnt(0) precede the MFMAs), so ph3 writes to buf0 only after ph1/ph2 reads
// are done; ph7 after ph5/ph6; ph1 after prev-iter ph5. RAW: vmcnt(4) at ph4/ph8
// (before the barrier) leaves only the 2 newest half-tiles in flight, so tile o
// (A staged prev ph7/8, B staged ph1/2) is resident before ph5, and tile 2I+2
// before the next ph1. Last iter: 2I+2/2I+3 clamp to 15 (re-stage, dest unread).
__global__ __launch_bounds__(512) void k_score_h(const _Float16* __restrict__ valh,
                                                 const _Float16* __restrict__ W1T,
                                                 const float* __restrict__ pq,
                                                 const float* __restrict__ V,
                                                 float* __restrict__ score) {
  __shared__ f32x4 ldsv[8192];  // 128 KiB
  char* lds = (char*)ldsv;

  const int tid = threadIdx.x;
  const int lane = tid & 63;
  const int w = tid >> 6;   // 0..7
  const int wr = w >> 2;    // 0..1  (m half)
  const int wc = w & 3;     // 0..3  (n quarter)
  const int quad = lane >> 4, l15 = lane & 15;

  // bijective XCD swizzle: 1024 blocks = 8 XCD * 128; per XCD: 32 m-tiles x 4 nc
  const int bid = blockIdx.x;
  const int sid = (bid & 7) * 128 + (bid >> 3);
  const int mt = sid >> 2;  // 0..255
  const int nc = sid & 3;   // 0..3
  const int m0 = mt * 256, n0 = nc * 256;

  // per-lane staging sources; source column pre-swizzled so linear LDS dest gets
  // phys col16 = (lane&7), holding logical col16 = (lane&7)^(row&7).
  const int r8 = lane >> 3, c8 = lane & 7;
  const int colel = (c8 ^ r8) * 8;
  const char* aS[2];
  const char* bS[2];
#pragma unroll
  for (int i = 0; i < 2; ++i) {
    const int seg = w * 2 + i;
    aS[i] = (const char*)valh + ((size_t)(m0 + seg * 8 + r8) * ND + colel) * 2;
    bS[i] = (const char*)W1T + ((size_t)(n0 + seg * 8 + r8) * ND + colel) * 2;
  }
  const int segL = w * 2048;  // LDS seg base (i=0); i=1 adds 1024

#define STG_A(t, h, p)                                                                \
  do {                                                                                \
    glds16(aS[0] + (size_t)(h)*262144 + (size_t)(t)*128,                              \
           lds + (p)*65536 + (h)*16384 + segL);                                       \
    glds16(aS[1] + (size_t)(h)*262144 + (size_t)(t)*128,                              \
           lds + (p)*65536 + (h)*16384 + segL + 1024);                                \
  } while (0)
#define STG_B(t, h, p)                                                                \
  do {                                                                                \
    glds16(bS[0] + (size_t)(h)*262144 + (size_t)(t)*128,                              \
           lds + (p)*65536 + 32768 + (h)*16384 + segL);                               \
    glds16(bS[1] + (size_t)(h)*262144 + (size_t)(t)*128,                              \
           lds + (p)*65536 + 32768 + (h)*16384 + segL + 1024);                        \
  } while (0)

  // fragment read offsets: row r byte = r*128; chunk ks*4+quad at pos ^(r&7)
  const int xr0 = ((quad + 0) ^ (l15 & 7)) * 16;
  const int xr1 = ((quad + 4) ^ (l15 & 7)) * 16;
  const int aRow = (wr * 128 + l15) * 128;         // + (mq*4+fm)*2048
  const int bRow = 32768 + (wc * 64 + l15) * 128;  // + fn*2048

  f16x8 af0[4][2], af1[4][2], bf[4][2];
  f32x4 acc[8][4];
#pragma unroll
  for (int i = 0; i < 8; ++i)
#pragma unroll
    for (int j = 0; j < 4; ++j) acc[i][j] = (f32x4){0.f, 0.f, 0.f, 0.f};

#define LDA(dst, p, mq)                                                               \
  do {                                                                                \
    _Pragma("unroll") for (int fm = 0; fm < 4; ++fm) {                                \
      const int rb = (p)*65536 + aRow + ((mq)*4 + fm) * 2048;                         \
      dst[fm][0] = *(const f16x8*)(lds + rb + xr0);                                   \
      dst[fm][1] = *(const f16x8*)(lds + rb + xr1);                                   \
    }                                                                                 \
  } while (0)
#define LDB(p)                                                                        \
  do {                                                                                \
    _Pragma("unroll") for (int fn = 0; fn < 4; ++fn) {                                \
      const int rb = (p)*65536 + bRow + fn * 2048;                                    \
      bf[fn][0] = *(const f16x8*)(lds + rb + xr0);                                    \
      bf[fn][1] = *(const f16x8*)(lds + rb + xr1);                                    \
    }                                                                                 \
  } while (0)
#define MM(a, mq, nq)                                                                 \
  do {                                                                                \
    _Pragma("unroll") for (int fm = 0; fm < 4; ++fm) {                                \
      _Pragma("unroll") for (int fn = 0; fn < 2; ++fn) {                              \
        acc[(mq)*4 + fm][(nq)*2 + fn] = __builtin_amdgcn_mfma_f32_16x16x32_f16(       \
            a[fm][0], bf[(nq)*2 + fn][0], acc[(mq)*4 + fm][(nq)*2 + fn], 0, 0, 0);    \
        acc[(mq)*4 + fm][(nq)*2 + fn] = __builtin_amdgcn_mfma_f32_16x16x32_f16(       \
            a[fm][1], bf[(nq)*2 + fn][1], acc[(mq)*4 + fm][(nq)*2 + fn], 0, 0, 0);    \
      }                                                                               \
    }                                                                                 \
  } while (0)
#define MIDBAR()                                                                      \
  do {                                                                                \
    __builtin_amdgcn_sched_barrier(0);                                                \
    __builtin_amdgcn_s_barrier();                                                     \
    asm volatile("s_waitcnt lgkmcnt(0)" ::: "memory");                                \
    __builtin_amdgcn_sched_barrier(0);                                                \
    __builtin_amdgcn_s_setprio(1);                                                    \
  } while (0)
#define ENDP()                                                                        \
  do {                                                                                \
    __builtin_amdgcn_s_setprio(0);                                                    \
    __builtin_amdgcn_sched_barrier(0);                                                \
    __builtin_amdgcn_s_barrier();                                                     \
  } while (0)
#define ENDPV()                                                                       \
  do {                                                                                \
    __builtin_amdgcn_s_setprio(0);                                                    \
    __builtin_amdgcn_sched_barrier(0);                                                \
    asm volatile("s_waitcnt vmcnt(4)" ::: "memory");                                  \
    __builtin_amdgcn_s_barrier();                                                     \
  } while (0)

  // prologue: tile0 (A0,A1,B0,B1 -> buf0) + tile1 A halves (-> buf1); keep the
  // 4 newest loads (tile1 A) in flight = steady state entering ph1.
  STG_A(0, 0, 0);
  STG_A(0, 1, 0);
  STG_B(0, 0, 0);
  STG_B(0, 1, 0);
  STG_A(1, 0, 1);
  STG_A(1, 1, 1);
  asm volatile("s_waitcnt vmcnt(4)" ::: "memory");
  __builtin_amdgcn_s_barrier();

  for (int I = 0; I < 8; ++I) {
    const int o = 2 * I + 1;
    const int t2 = (2 * I + 2 < 16) ? 2 * I + 2 : 15;
    const int t3 = (2 * I + 3 < 16) ? 2 * I + 3 : 15;
    // ---- even K-tile (buf0) ----
    LDA(af0, 0, 0);
    LDB(0);
    STG_B(o, 0, 1);
    MIDBAR();
    MM(af0, 0, 0);
    ENDP();

    LDA(af1, 0, 1);
    STG_B(o, 1, 1);
    MIDBAR();
    MM(af0, 0, 1);
    ENDP();

    STG_A(t2, 0, 0);
    MIDBAR();
    MM(af1, 1, 0);
    ENDP();

    STG_A(t2, 1, 0);
    MIDBAR();
    MM(af1, 1, 1);
    ENDPV();

    // ---- odd K-tile (buf1) ----
    LDA(af0, 1, 0);
    LDB(1);
    STG_B(t2, 0, 0);
    MIDBAR();
    MM(af0, 0, 0);
    ENDP();

    LDA(af1, 1, 1);
    STG_B(t2, 1, 0);
    MIDBAR();
    MM(af0, 0, 1);
    ENDP();

    STG_A(t3, 0, 1);
    MIDBAR();
    MM(af1, 1, 0);
    ENDP();

    STG_A(t3, 1, 1);
    MIDBAR();
    MM(af1, 1, 1);
    ENDPV();
  }

  // epilogue: C/D layout col=lane&15, row=quad*4+reg (m89/m91-verified)
  const int b = m0 >> 11;
  float vv[4], qq[4];
#pragma unroll
  for (int ci = 0; ci < 4; ++ci) {
    const int col = n0 + wc * 64 + ci * 16 + l15;
    vv[ci] = V[col];
    qq[ci] = pq[b * NU + col];
  }
#pragma unroll
  for (int ri = 0; ri < 8; ++ri) {
    float p0 = 0.f, p1 = 0.f, p2 = 0.f, p3 = 0.f;
#pragma unroll
    for (int ci = 0; ci < 4; ++ci) {
      f32x4 a = acc[ri][ci];
      p0 += fast_tanh(a.x + qq[ci]) * vv[ci];
      p1 += fast_tanh(a.y + qq[ci]) * vv[ci];
      p2 += fast_tanh(a.z + qq[ci]) * vv[ci];
      p3 += fast_tanh(a.w + qq[ci]) * vv[ci];
    }
#pragma unroll
    for (int mask = 1; mask < 16; mask <<= 1) {
      p0 += __shfl_xor(p0, mask);
      p1 += __shfl_xor(p1, mask);
      p2 += __shfl_xor(p2, mask);
      p3 += __shfl_xor(p3, mask);
    }
    if (l15 == 0) {
      const int rbase = m0 + wr * 128 + ri * 16 + quad * 4;
      atomicAdd(&score[rbase + 0], p0);
      atomicAdd(&score[rbase + 1], p1);
      atomicAdd(&score[rbase + 2], p2);
      atomicAdd(&score[rbase + 3], p3);
    }
  }
#undef STG_A
#undef STG_B
#undef LDA
#undef LDB
#undef MM
#undef MIDBAR
#undef ENDP
#undef ENDPV
}

// ---------------- fallback: fused GEMM with fp32 A staging (R2 kernel) ----------
__global__ __launch_bounds__(256) void k_score_f32(const float* __restrict__ values,
                                                   const unsigned short* __restrict__ W1T,
                                                   const float* __restrict__ pq,
                                                   const float* __restrict__ V,
                                                   float* __restrict__ score) {
  __shared__ f32x4 lds4[1536];
  char* lds = (char*)lds4;
  const int tid = threadIdx.x;
  const int lane = tid & 63;
  const int w = tid >> 6;
  const int wr = w >> 1, wc = w & 1;
  const int quad = lane >> 4, l15 = lane & 15;
  const int bid = blockIdx.x;
  const int xcd = bid & 7;
  const int local = bid >> 3;
  const int mt = xcd * 64 + (local >> 3);
  const int nc = local & 7;
  const int m0 = mt * 128, n0 = nc * 128;
  const char* aG[4];
  uint32_t aL[4];
  {
    const int p = lane & 7, r3 = lane >> 3;
    const int ca = p ^ r3;
#pragma unroll
    for (int i = 0; i < 4; ++i) {
      const int seg = w * 4 + i;
      const int mloc = seg * 8 + r3;
      aG[i] = (const char*)values + (size_t)(m0 + mloc) * (ND * 4) + ca * 16;
      aL[i] = seg * 1024;
    }
  }
  const char* bG[2];
  uint32_t bL[2];
  {
    const int cb = (lane & 3) ^ ((lane >> 3) & 3);
#pragma unroll
    for (int i = 0; i < 2; ++i) {
      const int seg = w * 2 + i;
      const int nloc = seg * 16 + (lane >> 2);
      bG[i] = (const char*)W1T + (size_t)(n0 + nloc) * (ND * 2) + cb * 16;
      bL[i] = 16384 + seg * 1024;
    }
  }
  uint32_t aOff[4][2], bOff[4];
  {
    const int p0 = (2 * quad) ^ (l15 & 7);
#pragma unroll
    for (int ri = 0; ri < 4; ++ri) {
      const int m = wr * 64 + ri * 16 + l15;
      aOff[ri][0] = m * 128 + p0 * 16;
      aOff[ri][1] = m * 128 + (p0 ^ 1) * 16;
    }
    const int pb = quad ^ ((l15 >> 1) & 3);
#pragma unroll
    for (int ci = 0; ci < 4; ++ci) {
      const int n = wc * 64 + ci * 16 + l15;
      bOff[ci] = 16384 + n * 64 + pb * 16;
    }
  }
  f32x4 acc[4][4];
#pragma unroll
  for (int i = 0; i < 4; ++i)
#pragma unroll
    for (int j = 0; j < 4; ++j) acc[i][j] = (f32x4){0.f, 0.f, 0.f, 0.f};
  for (int kt = 0; kt < 32; ++kt) {
    __syncthreads();
    const size_t aCol = (size_t)kt * 128;
    const size_t bCol = (size_t)kt * 64;
#pragma unroll
    for (int i = 0; i < 4; ++i) glds16(aG[i] + aCol, lds + aL[i]);
#pragma unroll
    for (int i = 0; i < 2; ++i) glds16(bG[i] + bCol, lds + bL[i]);
    __syncthreads();
    bf16x8 af[4];
#pragma unroll
    for (int ri = 0; ri < 4; ++ri) {
      f32x4 v0 = *(const f32x4*)(lds + aOff[ri][0]);
      f32x4 v1 = *(const f32x4*)(lds + aOff[ri][1]);
      union { uint32_t u[4]; bf16x8 v; } cvt;
      cvt.u[0] = pack_bf16_trunc(v0.x, v0.y);
      cvt.u[1] = pack_bf16_trunc(v0.z, v0.w);
      cvt.u[2] = pack_bf16_trunc(v1.x, v1.y);
      cvt.u[3] = pack_bf16_trunc(v1.z, v1.w);
      af[ri] = cvt.v;
    }
    bf16x8 bfg[4];
#pragma unroll
    for (int ci = 0; ci < 4; ++ci) {
      union { f32x4 f; bf16x8 v; } u;
      u.f = *(const f32x4*)(lds + bOff[ci]);
      bfg[ci] = u.v;
    }
#pragma unroll
    for (int ri = 0; ri < 4; ++ri)
#pragma unroll
      for (int ci = 0; ci < 4; ++ci)
        acc[ri][ci] =
            __builtin_amdgcn_mfma_f32_16x16x32_bf16(af[ri], bfg[ci], acc[ri][ci], 0, 0, 0);
  }
  const int b = m0 >> 11;
  float vv[4], qq[4];
#pragma unroll
  for (int ci = 0; ci < 4; ++ci) {
    const int col = n0 + wc * 64 + ci * 16 + l15;
    vv[ci] = V[col];
    qq[ci] = pq[b * NU + col];
  }
#pragma unroll
  for (int ri = 0; ri < 4; ++ri) {
    float p0 = 0.f, p1 = 0.f, p2 = 0.f, p3 = 0.f;
#pragma unroll
    for (int ci = 0; ci < 4; ++ci) {
      f32x4 a = acc[ri][ci];
      p0 += fast_tanh(a.x + qq[ci]) * vv[ci];
      p1 += fast_tanh(a.y + qq[ci]) * vv[ci];
      p2 += fast_tanh(a.z + qq[ci]) * vv[ci];
      p3 += fast_tanh(a.w + qq[ci]) * vv[ci];
    }
#pragma unroll
    for (int mask = 1; mask < 16; mask <<= 1) {
      p0 += __shfl_xor(p0, mask);
      p1 += __shfl_xor(p1, mask);
      p2 += __shfl_xor(p2, mask);
      p3 += __shfl_xor(p3, mask);
    }
    if (l15 == 0) {
      const int rbase = m0 + wr * 64 + ri * 16 + quad * 4;
      atomicAdd(&score[rbase + 0], p0);
      atomicAdd(&score[rbase + 1], p1);
      atomicAdd(&score[rbase + 2], p2);
      atomicAdd(&score[rbase + 3], p3);
    }
  }
}

// ---------------- softmax over S per batch; writes attention output -------------
__global__ __launch_bounds__(256) void k_softmax(const float* __restrict__ score,
                                                 float* __restrict__ attn) {
  __shared__ float red[8];
  const int b = blockIdx.x, tid = threadIdx.x;
  const int w = tid >> 6, lane = tid & 63;
  const float* s = score + b * NS;
  float v[8];
  float mx = -3.4e38f;
#pragma unroll
  for (int j = 0; j < 8; ++j) {
    v[j] = s[tid + j * 256];
    mx = fmaxf(mx, v[j]);
  }
#pragma unroll
  for (int mask = 1; mask < 64; mask <<= 1) mx = fmaxf(mx, __shfl_xor(mx, mask));
  if (lane == 0) red[w] = mx;
  __syncthreads();
  mx = fmaxf(fmaxf(red[0], red[1]), fmaxf(red[2], red[3]));
  float sum = 0.f;
#pragma unroll
  for (int j = 0; j < 8; ++j) {
    v[j] = __expf(v[j] - mx);
    sum += v[j];
  }
#pragma unroll
  for (int mask = 1; mask < 64; mask <<= 1) sum += __shfl_xor(sum, mask);
  if (lane == 0) red[4 + w] = sum;
  __syncthreads();
  const float inv = 1.0f / (red[4] + red[5] + red[6] + red[7]);
  float* o = attn + b * NS;
#pragma unroll
  for (int j = 0; j < 8; ++j) o[tid + j * 256] = v[j] * inv;
}

// ---------------- context partials from fp16 values -----------------------------
__global__ __launch_bounds__(128) void k_ctx_part_h(const _Float16* __restrict__ valh,
                                                    const float* __restrict__ attn,
                                                    float* __restrict__ part) {
  const int sc = blockIdx.x, b = blockIdx.y, t = threadIdx.x;
  const int row0 = b * NS + sc * 32;
  const int d8 = t * 8;
  const float* ab = attn + row0;  // wave-uniform -> s_load
  float acc[8];
#pragma unroll
  for (int i = 0; i < 8; ++i) acc[i] = 0.f;
  for (int s0 = 0; s0 < 32; s0 += 8) {
    uint4 r[8];
#pragma unroll
    for (int j = 0; j < 8; ++j)
      r[j] = *(const uint4*)(valh + (size_t)(row0 + s0 + j) * ND + d8);
#pragma unroll
    for (int j = 0; j < 8; ++j) {
      union { uint4 u; _Float16 h[8]; } c;
      c.u = r[j];
      const float a = ab[s0 + j];
#pragma unroll
      for (int i = 0; i < 8; ++i) acc[i] = fmaf(a, (float)c.h[i], acc[i]);
    }
  }
  float* o = part + (size_t)(b * 64 + sc) * ND + d8;
#pragma unroll
  for (int i = 0; i < 8; ++i) o[i] = acc[i];
}

// ---------------- fallback fp32 context partials --------------------------------
__global__ __launch_bounds__(256) void k_ctx_part_f32(const float* __restrict__ values,
                                                      const float* __restrict__ attn,
                                                      float* __restrict__ part) {
  const int sc = blockIdx.x, b = blockIdx.y, tid = threadIdx.x;
  const int s0 = sc * 64;
  const f32x4* vb = (const f32x4*)(values + (size_t)(b * NS + s0) * ND);
  const float* ab = attn + b * NS + s0;
  f32x4 acc0 = (f32x4){0.f, 0.f, 0.f, 0.f};
  f32x4 acc1 = acc0;
  for (int s = 0; s < 64; s += 8) {
    f32x4 v0 = vb[(size_t)(s + 0) * 256 + tid];
    f32x4 v1 = vb[(size_t)(s + 1) * 256 + tid];
    f32x4 v2 = vb[(size_t)(s + 2) * 256 + tid];
    f32x4 v3 = vb[(size_t)(s + 3) * 256 + tid];
    f32x4 v4 = vb[(size_t)(s + 4) * 256 + tid];
    f32x4 v5 = vb[(size_t)(s + 5) * 256 + tid];
    f32x4 v6 = vb[(size_t)(s + 6) * 256 + tid];
    f32x4 v7 = vb[(size_t)(s + 7) * 256 + tid];
    acc0 += ab[s + 0] * v0;
    acc1 += ab[s + 1] * v1;
    acc0 += ab[s + 2] * v2;
    acc1 += ab[s + 3] * v3;
    acc0 += ab[s + 4] * v4;
    acc1 += ab[s + 5] * v5;
    acc0 += ab[s + 6] * v6;
    acc1 += ab[s + 7] * v7;
  }
  *(f32x4*)(part + (size_t)(b * 32 + sc) * ND + tid * 4) = acc0 + acc1;
}

__global__ __launch_bounds__(256) void k_ctx_red(const float* __restrict__ part,
                                                 float* __restrict__ ctx, int count) {
  const int b = blockIdx.x, tid = threadIdx.x;
  f32x4 acc = (f32x4){0.f, 0.f, 0.f, 0.f};
  for (int sc = 0; sc < count; ++sc)
    acc += *(const f32x4*)(part + (size_t)(b * count + sc) * ND + tid * 4);
  *(f32x4*)(ctx + (size_t)b * ND + tid * 4) = acc;
}

extern "C" void kernel_launch(void* const* d_in, const int* in_sizes, int n_in,
                              void* d_out, int out_size, void* d_ws, size_t ws_size,
                              hipStream_t stream) {
  const float* query  = (const float*)d_in[0];
  const float* values = (const float*)d_in[1];
  const float* W1     = (const float*)d_in[2];
  const float* b1     = (const float*)d_in[3];
  const float* W2     = (const float*)d_in[4];
  const float* b2     = (const float*)d_in[5];
  const float* V      = (const float*)d_in[6];
  // d_in[7] = bV: uniform score shift -> cancels in softmax.

  float* ctx  = (float*)d_out;
  float* attn = (float*)d_out + NB * ND;

  char* ws = (char*)d_ws;
  const size_t SZ_VALH = (size_t)NM * ND * 2;  // 128 MiB
  const size_t need_h = SZ_VALH + 2097152 + 524288 + 131072 + 262144 + 8388608;

  if (ws_size >= need_h) {
    _Float16* valh   = (_Float16*)ws;
    _Float16* W1Th   = (_Float16*)(ws + SZ_VALH);
    float* pq_part   = (float*)(ws + SZ_VALH + 2097152);
    float* pq        = (float*)(ws + SZ_VALH + 2621440);
    float* score     = (float*)(ws + SZ_VALH + 2752512);
    float* part      = (float*)(ws + SZ_VALH + 3014656);

    hipMemsetAsync(score, 0, NM * sizeof(float), stream);
    k_cvt<<<4096, 256, 0, stream>>>(values, valh);
    k_w1t_h<<<dim3(16, 16), 256, 0, stream>>>(W1, W1Th);
    k_pq<<<dim3(4, NB), 256, 0, stream>>>(query, W2, pq_part);
    k_pq_red<<<NB, 256, 0, stream>>>(pq_part, b1, b2, pq);
    k_score_h<<<1024, 512, 0, stream>>>(valh, W1Th, pq, V, score);
    k_softmax<<<NB, 256, 0, stream>>>(score, attn);
    k_ctx_part_h<<<dim3(64, NB), 128, 0, stream>>>(valh, attn, part);
    k_ctx_red<<<NB, 256, 0, stream>>>(part, ctx, 64);
  } else {
    unsigned short* W1T = (unsigned short*)ws;
    float* pq_part = (float*)(ws + 2097152);
    float* pq      = (float*)(ws + 2621440);
    float* score   = (float*)(ws + 2752512);
    float* part    = (float*)(ws + 3014656);

    hipMemsetAsync(score, 0, NM * sizeof(float), stream);
    k_w1t<<<dim3(16, 16), 256, 0, stream>>>(W1, W1T);
    k_pq<<<dim3(4, NB), 256, 0, stream>>>(query, W2, pq_part);
    k_pq_red<<<NB, 256, 0, stream>>>(pq_part, b1, b2, pq);
    k_score_f32<<<4096, 256, 0, stream>>>(values, W1T, pq, V, score);
    k_softmax<<<NB, 256, 0, stream>>>(score, attn);
    k_ctx_part_f32<<<dim3(32, NB), 256, 0, stream>>>(values, attn, part);
    k_ctx_red<<<NB, 256, 0, stream>>>(part, ctx, 32);
  }
}

// Round 2
// 653.524 us; speedup vs baseline: 1.0133x; 1.0037x over previous
//
#include <hip/hip_runtime.h>
#include <stdint.h>

typedef float f32x4 __attribute__((ext_vector_type(4)));
typedef short bf16x8 __attribute__((ext_vector_type(8)));
typedef _Float16 f16x8 __attribute__((ext_vector_type(8)));

#define AS1 __attribute__((address_space(1)))
#define AS3 __attribute__((address_space(3)))

#define NB 32
#define NS 2048
#define ND 1024
#define NU 1024
#define NM (NB * NS)  // 65536 rows

// async 16B global->LDS (gfx950). LDS dest = wave-uniform base + lane*16.
__device__ __forceinline__ void glds16(const void* g, void* l) {
  __builtin_amdgcn_global_load_lds((const AS1 uint32_t*)g, (AS3 uint32_t*)l, 16, 0, 0);
}

__device__ __forceinline__ unsigned short bf16_rne(float f) {
  uint32_t u = __float_as_uint(f);
  u += 0x7fffu + ((u >> 16) & 1u);
  return (unsigned short)(u >> 16);
}

// two fp32 -> packed fp16 pair (RNE via v_cvt_f16_f32)
__device__ __forceinline__ uint32_t h2pack(float lo, float hi) {
  union { _Float16 h[2]; uint32_t u; } p;
  p.h[0] = (_Float16)lo;
  p.h[1] = (_Float16)hi;
  return p.u;
}

// (bf16_trunc(hi) << 16) | bf16_trunc(lo) in one v_perm_b32
__device__ __forceinline__ uint32_t pack_bf16_trunc(float lo, float hi) {
  return __builtin_amdgcn_perm(__float_as_uint(hi), __float_as_uint(lo), 0x07060302u);
}

__device__ __forceinline__ float fast_tanh(float x) {
  float e = __expf(2.0f * x);
  return 1.0f - 2.0f / (e + 1.0f);
}

// ---------------- values fp32 -> fp16 (RNE), 67.1M elems ------------------------
__global__ __launch_bounds__(256) void k_cvt(const float* __restrict__ values,
                                             _Float16* __restrict__ values_h) {
  const size_t gid = (size_t)blockIdx.x * 256 + threadIdx.x;
#pragma unroll 2
  for (int it = 0; it < 8; ++it) {
    const size_t e0 = gid * 8 + (size_t)it * 8388608;  // 1,048,576 thr * 8 elems
    f32x4 v0 = *(const f32x4*)(values + e0);
    f32x4 v1 = *(const f32x4*)(values + e0 + 4);
    uint4 o;
    o.x = h2pack(v0.x, v0.y);
    o.y = h2pack(v0.z, v0.w);
    o.z = h2pack(v1.x, v1.y);
    o.w = h2pack(v1.z, v1.w);
    *(uint4*)(values_h + e0) = o;
  }
}

// ---------------- W1[k][u] fp32 -> W1T[u][k] fp16 (RNE) -------------------------
__global__ __launch_bounds__(256) void k_w1t_h(const float* __restrict__ W1,
                                               _Float16* __restrict__ W1T) {
  __shared__ float t[64][65];
  const int n0 = blockIdx.x * 64, k0 = blockIdx.y * 64;
  const int tid = threadIdx.x;
  {
    const int r = tid >> 4, c4 = (tid & 15) << 2;
#pragma unroll
    for (int i = 0; i < 4; ++i) {
      f32x4 v = *(const f32x4*)(W1 + (size_t)(k0 + r + i * 16) * NU + n0 + c4);
      t[r + i * 16][c4 + 0] = v.x;
      t[r + i * 16][c4 + 1] = v.y;
      t[r + i * 16][c4 + 2] = v.z;
      t[r + i * 16][c4 + 3] = v.w;
    }
  }
  __syncthreads();
  const int rr = tid >> 2, cc = tid & 3;
  uint32_t o[8];
#pragma unroll
  for (int p = 0; p < 8; ++p)
    o[p] = h2pack(t[cc * 16 + 2 * p + 0][rr], t[cc * 16 + 2 * p + 1][rr]);
  _Float16* dst = W1T + (size_t)(n0 + rr) * ND + k0 + cc * 16;
  *(uint4*)(dst + 0) = make_uint4(o[0], o[1], o[2], o[3]);
  *(uint4*)(dst + 8) = make_uint4(o[4], o[5], o[6], o[7]);
}

// ---------------- W1 -> bf16 W1T (fallback path) --------------------------------
__global__ __launch_bounds__(256) void k_w1t(const float* __restrict__ W1,
                                             unsigned short* __restrict__ W1T) {
  __shared__ float t[64][65];
  const int n0 = blockIdx.x * 64, k0 = blockIdx.y * 64;
  const int tid = threadIdx.x;
  {
    const int r = tid >> 4, c4 = (tid & 15) << 2;
#pragma unroll
    for (int i = 0; i < 4; ++i) {
      f32x4 v = *(const f32x4*)(W1 + (size_t)(k0 + r + i * 16) * NU + n0 + c4);
      t[r + i * 16][c4 + 0] = v.x;
      t[r + i * 16][c4 + 1] = v.y;
      t[r + i * 16][c4 + 2] = v.z;
      t[r + i * 16][c4 + 3] = v.w;
    }
  }
  __syncthreads();
  const int rr = tid >> 2, cc = tid & 3;
  uint32_t o[8];
#pragma unroll
  for (int p = 0; p < 8; ++p) {
    float f0 = t[cc * 16 + 2 * p + 0][rr];
    float f1 = t[cc * 16 + 2 * p + 1][rr];
    o[p] = (uint32_t)bf16_rne(f0) | ((uint32_t)bf16_rne(f1) << 16);
  }
  unsigned short* dst = W1T + (size_t)(n0 + rr) * ND + k0 + cc * 16;
  *(uint4*)(dst + 0) = make_uint4(o[0], o[1], o[2], o[3]);
  *(uint4*)(dst + 8) = make_uint4(o[4], o[5], o[6], o[7]);
}

// ---------------- pq partials over k-chunks (f32x4 ILP) -------------------------
__global__ __launch_bounds__(256) void k_pq(const float* __restrict__ query,
                                            const float* __restrict__ W2,
                                            float* __restrict__ pq_part) {
  const int kc = blockIdx.x, b = blockIdx.y;
  const int u4 = threadIdx.x * 4;
  const float* q = query + b * ND + kc * 256;  // wave-uniform -> s_load
  f32x4 a0 = (f32x4){0.f, 0.f, 0.f, 0.f}, a1 = a0;
  const float* w = W2 + (size_t)kc * 256 * NU + u4;
  for (int k = 0; k < 256; k += 8) {
#pragma unroll
    for (int j = 0; j < 8; j += 2) {
      a0 += q[k + j + 0] * *(const f32x4*)(w + (size_t)(k + j + 0) * NU);
      a1 += q[k + j + 1] * *(const f32x4*)(w + (size_t)(k + j + 1) * NU);
    }
  }
  *(f32x4*)(pq_part + (size_t)(kc * NB + b) * NU + u4) = a0 + a1;
}

__global__ __launch_bounds__(256) void k_pq_red(const float* __restrict__ pq_part,
                                                const float* __restrict__ b1,
                                                const float* __restrict__ b2,
                                                float* __restrict__ pq) {
  const int b = blockIdx.x, u4 = threadIdx.x * 4;
  f32x4 acc = *(const f32x4*)(b1 + u4) + *(const f32x4*)(b2 + u4);
#pragma unroll
  for (int kc = 0; kc < 4; ++kc)
    acc += *(const f32x4*)(pq_part + (size_t)(kc * NB + b) * NU + u4);
  *(f32x4*)(pq + (size_t)b * NU + u4) = acc;
}

// ---------------- fused GEMM (values_h @ W1T_h) + tanh·V score ------------------
// 256x256 tile, BK=64, 8 waves (2M x 4N), 128 KiB LDS dbuf, 8-phase schedule with
// counted vmcnt (T3+T4), st-style XOR swizzle (T2), setprio around MFMA (T5).
//
// __launch_bounds__(512, 2): 8-wave block = 2 waves/SIMD minimum; cap = 256 VGPR.
// R1 post-mortem: bare (512) capped the allocator at 128 VGPR -> ~240-reg demand
// (acc 128 + frags 96 + addr) spilled to scratch: WRITE_SIZE 16.8->92.8 MB was
// spill traffic, MfmaUtil pinned at 26%. The (512,2) cap is exactly HK's 256^2
// config (8 waves x 256 VGPR = full file, 1 block/CU via 128 KiB LDS).
//
// LDS map: buf p (p = K-tile parity) at p*65536; A [256 rows][64k] at +0 (32 KiB,
// 128 B rows), B (=W1T rows) at +32768. Swizzle: phys col16 = logical ^ (row&7),
// applied on BOTH sides (pre-swizzled glds16 *source* column + swizzled ds_read).
//
// Stage slots (1 half-tile = 16 KiB = 2 glds16/wave per phase), iteration I
// computes tiles e=2I (buf0, ph1-4) and o=2I+1 (buf1, ph5-8):
//   ph1: B.h0(o)->buf1   ph2: B.h1(o)->buf1   ph3: A.h0(2I+2)->buf0
//   ph4: A.h1(2I+2)      ph5: B.h0(2I+2)      ph6: B.h1(2I+2)
//   ph7: A.h0(2I+3)->buf1 ph8: A.h1(2I+3)
// WAR: every phase's ds_reads complete before its post-MFMA barrier (mid-barrier +
// lgkmcnt(0) precede the MFMAs), so ph3 writes to buf0 only after ph1/ph2 reads
// are done; ph7 after ph5/ph6; ph1 after prev-iter ph5. RAW: vmcnt(4) at ph4/ph8
// (before the barrier) leaves only the 2 newest half-tiles in flight, so tile o
// (A staged prev ph7/8, B staged ph1/2) is resident before ph5, and tile 2I+2
// before the next ph1. Last iter: 2I+2/2I+3 clamp to 15 (re-stage, dest unread).
__global__ __launch_bounds__(512, 2) void k_score_h(const _Float16* __restrict__ valh,
                                                    const _Float16* __restrict__ W1T,
                                                    const float* __restrict__ pq,
                                                    const float* __restrict__ V,
                                                    float* __restrict__ score) {
  __shared__ f32x4 ldsv[8192];  // 128 KiB
  char* lds = (char*)ldsv;

  const int tid = threadIdx.x;
  const int lane = tid & 63;
  const int w = tid >> 6;   // 0..7
  const int wr = w >> 2;    // 0..1  (m half)
  const int wc = w & 3;     // 0..3  (n quarter)
  const int quad = lane >> 4, l15 = lane & 15;

  // bijective XCD swizzle: 1024 blocks = 8 XCD * 128; per XCD: 32 m-tiles x 4 nc
  const int bid = blockIdx.x;
  const int sid = (bid & 7) * 128 + (bid >> 3);
  const int mt = sid >> 2;  // 0..255
  const int nc = sid & 3;   // 0..3
  const int m0 = mt * 256, n0 = nc * 256;

  // per-lane staging sources; source column pre-swizzled so linear LDS dest gets
  // phys col16 = (lane&7), holding logical col16 = (lane&7)^(row&7).
  const int r8 = lane >> 3, c8 = lane & 7;
  const int colel = (c8 ^ r8) * 8;
  const char* aS[2];
  const char* bS[2];
#pragma unroll
  for (int i = 0; i < 2; ++i) {
    const int seg = w * 2 + i;
    aS[i] = (const char*)valh + ((size_t)(m0 + seg * 8 + r8) * ND + colel) * 2;
    bS[i] = (const char*)W1T + ((size_t)(n0 + seg * 8 + r8) * ND + colel) * 2;
  }
  const int segL = w * 2048;  // LDS seg base (i=0); i=1 adds 1024

#define STG_A(t, h, p)                                                                \
  do {                                                                                \
    glds16(aS[0] + (size_t)(h)*262144 + (size_t)(t)*128,                              \
           lds + (p)*65536 + (h)*16384 + segL);                                       \
    glds16(aS[1] + (size_t)(h)*262144 + (size_t)(t)*128,                              \
           lds + (p)*65536 + (h)*16384 + segL + 1024);                                \
  } while (0)
#define STG_B(t, h, p)                                                                \
  do {                                                                                \
    glds16(bS[0] + (size_t)(h)*262144 + (size_t)(t)*128,                              \
           lds + (p)*65536 + 32768 + (h)*16384 + segL);                               \
    glds16(bS[1] + (size_t)(h)*262144 + (size_t)(t)*128,                              \
           lds + (p)*65536 + 32768 + (h)*16384 + segL + 1024);                        \
  } while (0)

  // fragment read offsets: row r byte = r*128; chunk ks*4+quad at pos ^(r&7)
  const int xr0 = ((quad + 0) ^ (l15 & 7)) * 16;
  const int xr1 = ((quad + 4) ^ (l15 & 7)) * 16;
  const int aRow = (wr * 128 + l15) * 128;         // + (mq*4+fm)*2048
  const int bRow = 32768 + (wc * 64 + l15) * 128;  // + fn*2048

  f16x8 af0[4][2], af1[4][2], bf[4][2];
  f32x4 acc[8][4];
#pragma unroll
  for (int i = 0; i < 8; ++i)
#pragma unroll
    for (int j = 0; j < 4; ++j) acc[i][j] = (f32x4){0.f, 0.f, 0.f, 0.f};

#define LDA(dst, p, mq)                                                               \
  do {                                                                                \
    _Pragma("unroll") for (int fm = 0; fm < 4; ++fm) {                                \
      const int rb = (p)*65536 + aRow + ((mq)*4 + fm) * 2048;                         \
      dst[fm][0] = *(const f16x8*)(lds + rb + xr0);                                   \
      dst[fm][1] = *(const f16x8*)(lds + rb + xr1);                                   \
    }                                                                                 \
  } while (0)
#define LDB(p)                                                                        \
  do {                                                                                \
    _Pragma("unroll") for (int fn = 0; fn < 4; ++fn) {                                \
      const int rb = (p)*65536 + bRow + fn * 2048;                                    \
      bf[fn][0] = *(const f16x8*)(lds + rb + xr0);                                    \
      bf[fn][1] = *(const f16x8*)(lds + rb + xr1);                                    \
    }                                                                                 \
  } while (0)
#define MM(a, mq, nq)                                                                 \
  do {                                                                                \
    _Pragma("unroll") for (int fm = 0; fm < 4; ++fm) {                                \
      _Pragma("unroll") for (int fn = 0; fn < 2; ++fn) {                              \
        acc[(mq)*4 + fm][(nq)*2 + fn] = __builtin_amdgcn_mfma_f32_16x16x32_f16(       \
            a[fm][0], bf[(nq)*2 + fn][0], acc[(mq)*4 + fm][(nq)*2 + fn], 0, 0, 0);    \
        acc[(mq)*4 + fm][(nq)*2 + fn] = __builtin_amdgcn_mfma_f32_16x16x32_f16(       \
            a[fm][1], bf[(nq)*2 + fn][1], acc[(mq)*4 + fm][(nq)*2 + fn], 0, 0, 0);    \
      }                                                                               \
    }                                                                                 \
  } while (0)
#define MIDBAR()                                                                      \
  do {                                                                                \
    __builtin_amdgcn_sched_barrier(0);                                                \
    __builtin_amdgcn_s_barrier();                                                     \
    asm volatile("s_waitcnt lgkmcnt(0)" ::: "memory");                                \
    __builtin_amdgcn_sched_barrier(0);                                                \
    __builtin_amdgcn_s_setprio(1);                                                    \
  } while (0)
#define ENDP()                                                                        \
  do {                                                                                \
    __builtin_amdgcn_s_setprio(0);                                                    \
    __builtin_amdgcn_sched_barrier(0);                                                \
    __builtin_amdgcn_s_barrier();                                                     \
  } while (0)
#define ENDPV()                                                                       \
  do {                                                                                \
    __builtin_amdgcn_s_setprio(0);                                                    \
    __builtin_amdgcn_sched_barrier(0);                                                \
    asm volatile("s_waitcnt vmcnt(4)" ::: "memory");                                  \
    __builtin_amdgcn_s_barrier();                                                     \
  } while (0)

  // prologue: tile0 (A0,A1,B0,B1 -> buf0) + tile1 A halves (-> buf1); keep the
  // 4 newest loads (tile1 A) in flight = steady state entering ph1.
  STG_A(0, 0, 0);
  STG_A(0, 1, 0);
  STG_B(0, 0, 0);
  STG_B(0, 1, 0);
  STG_A(1, 0, 1);
  STG_A(1, 1, 1);
  asm volatile("s_waitcnt vmcnt(4)" ::: "memory");
  __builtin_amdgcn_s_barrier();

  for (int I = 0; I < 8; ++I) {
    const int o = 2 * I + 1;
    const int t2 = (2 * I + 2 < 16) ? 2 * I + 2 : 15;
    const int t3 = (2 * I + 3 < 16) ? 2 * I + 3 : 15;
    // ---- even K-tile (buf0) ----
    LDA(af0, 0, 0);
    LDB(0);
    STG_B(o, 0, 1);
    MIDBAR();
    MM(af0, 0, 0);
    ENDP();

    LDA(af1, 0, 1);
    STG_B(o, 1, 1);
    MIDBAR();
    MM(af0, 0, 1);
    ENDP();

    STG_A(t2, 0, 0);
    MIDBAR();
    MM(af1, 1, 0);
    ENDP();

    STG_A(t2, 1, 0);
    MIDBAR();
    MM(af1, 1, 1);
    ENDPV();

    // ---- odd K-tile (buf1) ----
    LDA(af0, 1, 0);
    LDB(1);
    STG_B(t2, 0, 0);
    MIDBAR();
    MM(af0, 0, 0);
    ENDP();

    LDA(af1, 1, 1);
    STG_B(t2, 1, 0);
    MIDBAR();
    MM(af0, 0, 1);
    ENDP();

    STG_A(t3, 0, 1);
    MIDBAR();
    MM(af1, 1, 0);
    ENDP();

    STG_A(t3, 1, 1);
    MIDBAR();
    MM(af1, 1, 1);
    ENDPV();
  }

  // epilogue: C/D layout col=lane&15, row=quad*4+reg (m89/m91-verified)
  const int b = m0 >> 11;
  float vv[4], qq[4];
#pragma unroll
  for (int ci = 0; ci < 4; ++ci) {
    const int col = n0 + wc * 64 + ci * 16 + l15;
    vv[ci] = V[col];
    qq[ci] = pq[b * NU + col];
  }
#pragma unroll
  for (int ri = 0; ri < 8; ++ri) {
    float p0 = 0.f, p1 = 0.f, p2 = 0.f, p3 = 0.f;
#pragma unroll
    for (int ci = 0; ci < 4; ++ci) {
      f32x4 a = acc[ri][ci];
      p0 += fast_tanh(a.x + qq[ci]) * vv[ci];
      p1 += fast_tanh(a.y + qq[ci]) * vv[ci];
      p2 += fast_tanh(a.z + qq[ci]) * vv[ci];
      p3 += fast_tanh(a.w + qq[ci]) * vv[ci];
    }
#pragma unroll
    for (int mask = 1; mask < 16; mask <<= 1) {
      p0 += __shfl_xor(p0, mask);
      p1 += __shfl_xor(p1, mask);
      p2 += __shfl_xor(p2, mask);
      p3 += __shfl_xor(p3, mask);
    }
    if (l15 == 0) {
      const int rbase = m0 + wr * 128 + ri * 16 + quad * 4;
      atomicAdd(&score[rbase + 0], p0);
      atomicAdd(&score[rbase + 1], p1);
      atomicAdd(&score[rbase + 2], p2);
      atomicAdd(&score[rbase + 3], p3);
    }
  }
#undef STG_A
#undef STG_B
#undef LDA
#undef LDB
#undef MM
#undef MIDBAR
#undef ENDP
#undef ENDPV
}

// ---------------- fallback: fused GEMM with fp32 A staging (R2 kernel) ----------
__global__ __launch_bounds__(256) void k_score_f32(const float* __restrict__ values,
                                                   const unsigned short* __restrict__ W1T,
                                                   const float* __restrict__ pq,
                                                   const float* __restrict__ V,
                                                   float* __restrict__ score) {
  __shared__ f32x4 lds4[1536];
  char* lds = (char*)lds4;
  const int tid = threadIdx.x;
  const int lane = tid & 63;
  const int w = tid >> 6;
  const int wr = w >> 1, wc = w & 1;
  const int quad = lane >> 4, l15 = lane & 15;
  const int bid = blockIdx.x;
  const int xcd = bid & 7;
  const int local = bid >> 3;
  const int mt = xcd * 64 + (local >> 3);
  const int nc = local & 7;
  const int m0 = mt * 128, n0 = nc * 128;
  const char* aG[4];
  uint32_t aL[4];
  {
    const int p = lane & 7, r3 = lane >> 3;
    const int ca = p ^ r3;
#pragma unroll
    for (int i = 0; i < 4; ++i) {
      const int seg = w * 4 + i;
      const int mloc = seg * 8 + r3;
      aG[i] = (const char*)values + (size_t)(m0 + mloc) * (ND * 4) + ca * 16;
      aL[i] = seg * 1024;
    }
  }
  const char* bG[2];
  uint32_t bL[2];
  {
    const int cb = (lane & 3) ^ ((lane >> 3) & 3);
#pragma unroll
    for (int i = 0; i < 2; ++i) {
      const int seg = w * 2 + i;
      const int nloc = seg * 16 + (lane >> 2);
      bG[i] = (const char*)W1T + (size_t)(n0 + nloc) * (ND * 2) + cb * 16;
      bL[i] = 16384 + seg * 1024;
    }
  }
  uint32_t aOff[4][2], bOff[4];
  {
    const int p0 = (2 * quad) ^ (l15 & 7);
#pragma unroll
    for (int ri = 0; ri < 4; ++ri) {
      const int m = wr * 64 + ri * 16 + l15;
      aOff[ri][0] = m * 128 + p0 * 16;
      aOff[ri][1] = m * 128 + (p0 ^ 1) * 16;
    }
    const int pb = quad ^ ((l15 >> 1) & 3);
#pragma unroll
    for (int ci = 0; ci < 4; ++ci) {
      const int n = wc * 64 + ci * 16 + l15;
      bOff[ci] = 16384 + n * 64 + pb * 16;
    }
  }
  f32x4 acc[4][4];
#pragma unroll
  for (int i = 0; i < 4; ++i)
#pragma unroll
    for (int j = 0; j < 4; ++j) acc[i][j] = (f32x4){0.f, 0.f, 0.f, 0.f};
  for (int kt = 0; kt < 32; ++kt) {
    __syncthreads();
    const size_t aCol = (size_t)kt * 128;
    const size_t bCol = (size_t)kt * 64;
#pragma unroll
    for (int i = 0; i < 4; ++i) glds16(aG[i] + aCol, lds + aL[i]);
#pragma unroll
    for (int i = 0; i < 2; ++i) glds16(bG[i] + bCol, lds + bL[i]);
    __syncthreads();
    bf16x8 af[4];
#pragma unroll
    for (int ri = 0; ri < 4; ++ri) {
      f32x4 v0 = *(const f32x4*)(lds + aOff[ri][0]);
      f32x4 v1 = *(const f32x4*)(lds + aOff[ri][1]);
      union { uint32_t u[4]; bf16x8 v; } cvt;
      cvt.u[0] = pack_bf16_trunc(v0.x, v0.y);
      cvt.u[1] = pack_bf16_trunc(v0.z, v0.w);
      cvt.u[2] = pack_bf16_trunc(v1.x, v1.y);
      cvt.u[3] = pack_bf16_trunc(v1.z, v1.w);
      af[ri] = cvt.v;
    }
    bf16x8 bfg[4];
#pragma unroll
    for (int ci = 0; ci < 4; ++ci) {
      union { f32x4 f; bf16x8 v; } u;
      u.f = *(const f32x4*)(lds + bOff[ci]);
      bfg[ci] = u.v;
    }
#pragma unroll
    for (int ri = 0; ri < 4; ++ri)
#pragma unroll
      for (int ci = 0; ci < 4; ++ci)
        acc[ri][ci] =
            __builtin_amdgcn_mfma_f32_16x16x32_bf16(af[ri], bfg[ci], acc[ri][ci], 0, 0, 0);
  }
  const int b = m0 >> 11;
  float vv[4], qq[4];
#pragma unroll
  for (int ci = 0; ci < 4; ++ci) {
    const int col = n0 + wc * 64 + ci * 16 + l15;
    vv[ci] = V[col];
    qq[ci] = pq[b * NU + col];
  }
#pragma unroll
  for (int ri = 0; ri < 4; ++ri) {
    float p0 = 0.f, p1 = 0.f, p2 = 0.f, p3 = 0.f;
#pragma unroll
    for (int ci = 0; ci < 4; ++ci) {
      f32x4 a = acc[ri][ci];
      p0 += fast_tanh(a.x + qq[ci]) * vv[ci];
      p1 += fast_tanh(a.y + qq[ci]) * vv[ci];
      p2 += fast_tanh(a.z + qq[ci]) * vv[ci];
      p3 += fast_tanh(a.w + qq[ci]) * vv[ci];
    }
#pragma unroll
    for (int mask = 1; mask < 16; mask <<= 1) {
      p0 += __shfl_xor(p0, mask);
      p1 += __shfl_xor(p1, mask);
      p2 += __shfl_xor(p2, mask);
      p3 += __shfl_xor(p3, mask);
    }
    if (l15 == 0) {
      const int rbase = m0 + wr * 64 + ri * 16 + quad * 4;
      atomicAdd(&score[rbase + 0], p0);
      atomicAdd(&score[rbase + 1], p1);
      atomicAdd(&score[rbase + 2], p2);
      atomicAdd(&score[rbase + 3], p3);
    }
  }
}

// ---------------- softmax over S per batch; writes attention output -------------
__global__ __launch_bounds__(256) void k_softmax(const float* __restrict__ score,
                                                 float* __restrict__ attn) {
  __shared__ float red[8];
  const int b = blockIdx.x, tid = threadIdx.x;
  const int w = tid >> 6, lane = tid & 63;
  const float* s = score + b * NS;
  float v[8];
  float mx = -3.4e38f;
#pragma unroll
  for (int j = 0; j < 8; ++j) {
    v[j] = s[tid + j * 256];
    mx = fmaxf(mx, v[j]);
  }
#pragma unroll
  for (int mask = 1; mask < 64; mask <<= 1) mx = fmaxf(mx, __shfl_xor(mx, mask));
  if (lane == 0) red[w] = mx;
  __syncthreads();
  mx = fmaxf(fmaxf(red[0], red[1]), fmaxf(red[2], red[3]));
  float sum = 0.f;
#pragma unroll
  for (int j = 0; j < 8; ++j) {
    v[j] = __expf(v[j] - mx);
    sum += v[j];
  }
#pragma unroll
  for (int mask = 1; mask < 64; mask <<= 1) sum += __shfl_xor(sum, mask);
  if (lane == 0) red[4 + w] = sum;
  __syncthreads();
  const float inv = 1.0f / (red[4] + red[5] + red[6] + red[7]);
  float* o = attn + b * NS;
#pragma unroll
  for (int j = 0; j < 8; ++j) o[tid + j * 256] = v[j] * inv;
}

// ---------------- context partials from fp16 values -----------------------------
__global__ __launch_bounds__(128) void k_ctx_part_h(const _Float16* __restrict__ valh,
                                                    const float* __restrict__ attn,
                                                    float* __restrict__ part) {
  const int sc = blockIdx.x, b = blockIdx.y, t = threadIdx.x;
  const int row0 = b * NS + sc * 32;
  const int d8 = t * 8;
  const float* ab = attn + row0;  // wave-uniform -> s_load
  float acc[8];
#pragma unroll
  for (int i = 0; i < 8; ++i) acc[i] = 0.f;
  for (int s0 = 0; s0 < 32; s0 += 8) {
    uint4 r[8];
#pragma unroll
    for (int j = 0; j < 8; ++j)
      r[j] = *(const uint4*)(valh + (size_t)(row0 + s0 + j) * ND + d8);
#pragma unroll
    for (int j = 0; j < 8; ++j) {
      union { uint4 u; _Float16 h[8]; } c;
      c.u = r[j];
      const float a = ab[s0 + j];
#pragma unroll
      for (int i = 0; i < 8; ++i) acc[i] = fmaf(a, (float)c.h[i], acc[i]);
    }
  }
  float* o = part + (size_t)(b * 64 + sc) * ND + d8;
#pragma unroll
  for (int i = 0; i < 8; ++i) o[i] = acc[i];
}

// ---------------- fallback fp32 context partials --------------------------------
__global__ __launch_bounds__(256) void k_ctx_part_f32(const float* __restrict__ values,
                                                      const float* __restrict__ attn,
                                                      float* __restrict__ part) {
  const int sc = blockIdx.x, b = blockIdx.y, tid = threadIdx.x;
  const int s0 = sc * 64;
  const f32x4* vb = (const f32x4*)(values + (size_t)(b * NS + s0) * ND);
  const float* ab = attn + b * NS + s0;
  f32x4 acc0 = (f32x4){0.f, 0.f, 0.f, 0.f};
  f32x4 acc1 = acc0;
  for (int s = 0; s < 64; s += 8) {
    f32x4 v0 = vb[(size_t)(s + 0) * 256 + tid];
    f32x4 v1 = vb[(size_t)(s + 1) * 256 + tid];
    f32x4 v2 = vb[(size_t)(s + 2) * 256 + tid];
    f32x4 v3 = vb[(size_t)(s + 3) * 256 + tid];
    f32x4 v4 = vb[(size_t)(s + 4) * 256 + tid];
    f32x4 v5 = vb[(size_t)(s + 5) * 256 + tid];
    f32x4 v6 = vb[(size_t)(s + 6) * 256 + tid];
    f32x4 v7 = vb[(size_t)(s + 7) * 256 + tid];
    acc0 += ab[s + 0] * v0;
    acc1 += ab[s + 1] * v1;
    acc0 += ab[s + 2] * v2;
    acc1 += ab[s + 3] * v3;
    acc0 += ab[s + 4] * v4;
    acc1 += ab[s + 5] * v5;
    acc0 += ab[s + 6] * v6;
    acc1 += ab[s + 7] * v7;
  }
  *(f32x4*)(part + (size_t)(b * 32 + sc) * ND + tid * 4) = acc0 + acc1;
}

__global__ __launch_bounds__(256) void k_ctx_red(const float* __restrict__ part,
                                                 float* __restrict__ ctx, int count) {
  const int b = blockIdx.x, tid = threadIdx.x;
  f32x4 acc = (f32x4){0.f, 0.f, 0.f, 0.f};
  for (int sc = 0; sc < count; ++sc)
    acc += *(const f32x4*)(part + (size_t)(b * count + sc) * ND + tid * 4);
  *(f32x4*)(ctx + (size_t)b * ND + tid * 4) = acc;
}

extern "C" void kernel_launch(void* const* d_in, const int* in_sizes, int n_in,
                              void* d_out, int out_size, void* d_ws, size_t ws_size,
                              hipStream_t stream) {
  const float* query  = (const float*)d_in[0];
  const float* values = (const float*)d_in[1];
  const float* W1     = (const float*)d_in[2];
  const float* b1     = (const float*)d_in[3];
  const float* W2     = (const float*)d_in[4];
  const float* b2     = (const float*)d_in[5];
  const float* V      = (const float*)d_in[6];
  // d_in[7] = bV: uniform score shift -> cancels in softmax.

  float* ctx  = (float*)d_out;
  float* attn = (float*)d_out + NB * ND;

  char* ws = (char*)d_ws;
  const size_t SZ_VALH = (size_t)NM * ND * 2;  // 128 MiB
  const size_t need_h = SZ_VALH + 2097152 + 524288 + 131072 + 262144 + 8388608;

  if (ws_size >= need_h) {
    _Float16* valh   = (_Float16*)ws;
    _Float16* W1Th   = (_Float16*)(ws + SZ_VALH);
    float* pq_part   = (float*)(ws + SZ_VALH + 2097152);
    float* pq        = (float*)(ws + SZ_VALH + 2621440);
    float* score     = (float*)(ws + SZ_VALH + 2752512);
    float* part      = (float*)(ws + SZ_VALH + 3014656);

    hipMemsetAsync(score, 0, NM * sizeof(float), stream);
    k_cvt<<<4096, 256, 0, stream>>>(values, valh);
    k_w1t_h<<<dim3(16, 16), 256, 0, stream>>>(W1, W1Th);
    k_pq<<<dim3(4, NB), 256, 0, stream>>>(query, W2, pq_part);
    k_pq_red<<<NB, 256, 0, stream>>>(pq_part, b1, b2, pq);
    k_score_h<<<1024, 512, 0, stream>>>(valh, W1Th, pq, V, score);
    k_softmax<<<NB, 256, 0, stream>>>(score, attn);
    k_ctx_part_h<<<dim3(64, NB), 128, 0, stream>>>(valh, attn, part);
    k_ctx_red<<<NB, 256, 0, stream>>>(part, ctx, 64);
  } else {
    unsigned short* W1T = (unsigned short*)ws;
    float* pq_part = (float*)(ws + 2097152);
    float* pq      = (float*)(ws + 2621440);
    float* score   = (float*)(ws + 2752512);
    float* part    = (float*)(ws + 3014656);

    hipMemsetAsync(score, 0, NM * sizeof(float), stream);
    k_w1t<<<dim3(16, 16), 256, 0, stream>>>(W1, W1T);
    k_pq<<<dim3(4, NB), 256, 0, stream>>>(query, W2, pq_part);
    k_pq_red<<<NB, 256, 0, stream>>>(pq_part, b1, b2, pq);
    k_score_f32<<<4096, 256, 0, stream>>>(values, W1T, pq, V, score);
    k_softmax<<<NB, 256, 0, stream>>>(score, attn);
    k_ctx_part_f32<<<dim3(32, NB), 256, 0, stream>>>(values, attn, part);
    k_ctx_red<<<NB, 256, 0, stream>>>(part, ctx, 32);
  }
}

// Round 3
// 616.759 us; speedup vs baseline: 1.0737x; 1.0596x over previous
//
#include <hip/hip_runtime.h>
#include <stdint.h>

typedef float f32x4 __attribute__((ext_vector_type(4)));
typedef short bf16x8 __attribute__((ext_vector_type(8)));
typedef _Float16 f16x8 __attribute__((ext_vector_type(8)));

#define AS1 __attribute__((address_space(1)))
#define AS3 __attribute__((address_space(3)))

#define NB 32
#define NS 2048
#define ND 1024
#define NU 1024
#define NM (NB * NS)  // 65536 rows

// async 16B global->LDS (gfx950). LDS dest = wave-uniform base + lane*16.
__device__ __forceinline__ void glds16(const void* g, void* l) {
  __builtin_amdgcn_global_load_lds((const AS1 uint32_t*)g, (AS3 uint32_t*)l, 16, 0, 0);
}

__device__ __forceinline__ unsigned short bf16_rne(float f) {
  uint32_t u = __float_as_uint(f);
  u += 0x7fffu + ((u >> 16) & 1u);
  return (unsigned short)(u >> 16);
}

// two fp32 -> packed fp16 pair (RNE via v_cvt_f16_f32)
__device__ __forceinline__ uint32_t h2pack(float lo, float hi) {
  union { _Float16 h[2]; uint32_t u; } p;
  p.h[0] = (_Float16)lo;
  p.h[1] = (_Float16)hi;
  return p.u;
}

// (bf16_trunc(hi) << 16) | bf16_trunc(lo) in one v_perm_b32
__device__ __forceinline__ uint32_t pack_bf16_trunc(float lo, float hi) {
  return __builtin_amdgcn_perm(__float_as_uint(hi), __float_as_uint(lo), 0x07060302u);
}

__device__ __forceinline__ float fast_tanh(float x) {
  float e = __expf(2.0f * x);
  return 1.0f - 2.0f / (e + 1.0f);
}

// ---------------- values fp32 -> fp16 (RNE), 67.1M elems ------------------------
__global__ __launch_bounds__(256) void k_cvt(const float* __restrict__ values,
                                             _Float16* __restrict__ values_h) {
  const size_t gid = (size_t)blockIdx.x * 256 + threadIdx.x;
#pragma unroll 2
  for (int it = 0; it < 8; ++it) {
    const size_t e0 = gid * 8 + (size_t)it * 8388608;  // 1,048,576 thr * 8 elems
    f32x4 v0 = *(const f32x4*)(values + e0);
    f32x4 v1 = *(const f32x4*)(values + e0 + 4);
    uint4 o;
    o.x = h2pack(v0.x, v0.y);
    o.y = h2pack(v0.z, v0.w);
    o.z = h2pack(v1.x, v1.y);
    o.w = h2pack(v1.z, v1.w);
    *(uint4*)(values_h + e0) = o;
  }
}

// ---------------- W1[k][u] fp32 -> W1T[u][k] fp16 (RNE) -------------------------
__global__ __launch_bounds__(256) void k_w1t_h(const float* __restrict__ W1,
                                               _Float16* __restrict__ W1T) {
  __shared__ float t[64][65];
  const int n0 = blockIdx.x * 64, k0 = blockIdx.y * 64;
  const int tid = threadIdx.x;
  {
    const int r = tid >> 4, c4 = (tid & 15) << 2;
#pragma unroll
    for (int i = 0; i < 4; ++i) {
      f32x4 v = *(const f32x4*)(W1 + (size_t)(k0 + r + i * 16) * NU + n0 + c4);
      t[r + i * 16][c4 + 0] = v.x;
      t[r + i * 16][c4 + 1] = v.y;
      t[r + i * 16][c4 + 2] = v.z;
      t[r + i * 16][c4 + 3] = v.w;
    }
  }
  __syncthreads();
  const int rr = tid >> 2, cc = tid & 3;
  uint32_t o[8];
#pragma unroll
  for (int p = 0; p < 8; ++p)
    o[p] = h2pack(t[cc * 16 + 2 * p + 0][rr], t[cc * 16 + 2 * p + 1][rr]);
  _Float16* dst = W1T + (size_t)(n0 + rr) * ND + k0 + cc * 16;
  *(uint4*)(dst + 0) = make_uint4(o[0], o[1], o[2], o[3]);
  *(uint4*)(dst + 8) = make_uint4(o[4], o[5], o[6], o[7]);
}

// ---------------- W1 -> bf16 W1T (fallback path) --------------------------------
__global__ __launch_bounds__(256) void k_w1t(const float* __restrict__ W1,
                                             unsigned short* __restrict__ W1T) {
  __shared__ float t[64][65];
  const int n0 = blockIdx.x * 64, k0 = blockIdx.y * 64;
  const int tid = threadIdx.x;
  {
    const int r = tid >> 4, c4 = (tid & 15) << 2;
#pragma unroll
    for (int i = 0; i < 4; ++i) {
      f32x4 v = *(const f32x4*)(W1 + (size_t)(k0 + r + i * 16) * NU + n0 + c4);
      t[r + i * 16][c4 + 0] = v.x;
      t[r + i * 16][c4 + 1] = v.y;
      t[r + i * 16][c4 + 2] = v.z;
      t[r + i * 16][c4 + 3] = v.w;
    }
  }
  __syncthreads();
  const int rr = tid >> 2, cc = tid & 3;
  uint32_t o[8];
#pragma unroll
  for (int p = 0; p < 8; ++p) {
    float f0 = t[cc * 16 + 2 * p + 0][rr];
    float f1 = t[cc * 16 + 2 * p + 1][rr];
    o[p] = (uint32_t)bf16_rne(f0) | ((uint32_t)bf16_rne(f1) << 16);
  }
  unsigned short* dst = W1T + (size_t)(n0 + rr) * ND + k0 + cc * 16;
  *(uint4*)(dst + 0) = make_uint4(o[0], o[1], o[2], o[3]);
  *(uint4*)(dst + 8) = make_uint4(o[4], o[5], o[6], o[7]);
}

// ---------------- pq partials over k-chunks (f32x4 ILP) -------------------------
__global__ __launch_bounds__(256) void k_pq(const float* __restrict__ query,
                                            const float* __restrict__ W2,
                                            float* __restrict__ pq_part) {
  const int kc = blockIdx.x, b = blockIdx.y;
  const int u4 = threadIdx.x * 4;
  const float* q = query + b * ND + kc * 256;  // wave-uniform -> s_load
  f32x4 a0 = (f32x4){0.f, 0.f, 0.f, 0.f}, a1 = a0;
  const float* w = W2 + (size_t)kc * 256 * NU + u4;
  for (int k = 0; k < 256; k += 8) {
#pragma unroll
    for (int j = 0; j < 8; j += 2) {
      a0 += q[k + j + 0] * *(const f32x4*)(w + (size_t)(k + j + 0) * NU);
      a1 += q[k + j + 1] * *(const f32x4*)(w + (size_t)(k + j + 1) * NU);
    }
  }
  *(f32x4*)(pq_part + (size_t)(kc * NB + b) * NU + u4) = a0 + a1;
}

__global__ __launch_bounds__(256) void k_pq_red(const float* __restrict__ pq_part,
                                                const float* __restrict__ b1,
                                                const float* __restrict__ b2,
                                                float* __restrict__ pq) {
  const int b = blockIdx.x, u4 = threadIdx.x * 4;
  f32x4 acc = *(const f32x4*)(b1 + u4) + *(const f32x4*)(b2 + u4);
#pragma unroll
  for (int kc = 0; kc < 4; ++kc)
    acc += *(const f32x4*)(pq_part + (size_t)(kc * NB + b) * NU + u4);
  *(f32x4*)(pq + (size_t)b * NU + u4) = acc;
}

// ---------------- fused GEMM (values_h @ W1T_h) + tanh·V score ------------------
// 256x256 tile, BK=64, 8 waves (2M x 4N), 128 KiB LDS dbuf, 8-phase schedule with
// counted vmcnt (T3+T4), XOR swizzle (T2), setprio (T5).
//
// R2 post-mortem: __launch_bounds__(512,2) left VGPR cap at 128 (VGPR_Count=128,
// WRITE_SIZE 92.5 MB spill, both bit-identical to R1). Fix from both ends:
//  (a) raw LLVM attrs: amdgpu_flat_work_group_size(512,512)+amdgpu_waves_per_eu(2,2)
//      -> exactly 2 waves/EU -> 256 VGPR budget (HK 256^2 config).
//  (b) single A-fragment buffer (saves 32 VGPRs): A staged in QUARTERS (64 rows).
//      mq=0 consumes A-rows {0-63,128-191} = q0,q2 (wr=0/1) in ph1-2, so ph3 may
//      overwrite q0,q2 with tile T+2 while LDA(af,mq=1) reads disjoint q1,q3;
//      ph4 stages q1,q3 after ph3's lgkmcnt(0)+barrier retires those reads.
//      Tally: frags 64 + acc 128 + addr ~25 ~= 220 <= 256.
//
// Phases per K-tile T (buf p=T&1), staging B(T+1)->buf p^1, A(T+2)->buf p:
//   ph1: LDA(af,p,0)+LDB(p) | STG B(T+1).h0 | MM(0,0)
//   ph2:                      STG B(T+1).h1 | MM(0,1)
//   ph3: LDA(af,p,1)        | STG A(T+2).q0,q2 | MM(1,0)
//   ph4:                      STG A(T+2).q1,q3 | MM(1,1) | vmcnt(4)+bar
// In-flight at ENDPV: A(T+1)4 + B(T+1)4 + A(T+2)4 = 12; drain 8 -> vmcnt(4)
// leaves A(T+2) in flight (steady state; prologue establishes A(1) in flight).
// Tail (T=14,15): clamped re-stages land in unread regions / same bytes.
__global__ __attribute__((amdgpu_flat_work_group_size(512, 512),
                          amdgpu_waves_per_eu(2, 2)))
void k_score_h(const _Float16* __restrict__ valh,
               const _Float16* __restrict__ W1T,
               const float* __restrict__ pq,
               const float* __restrict__ V,
               float* __restrict__ score) {
  __shared__ f32x4 ldsv[8192];  // 128 KiB
  char* lds = (char*)ldsv;

  const int tid = threadIdx.x;
  const int lane = tid & 63;
  const int w = tid >> 6;   // 0..7
  const int wr = w >> 2;    // 0..1  (m half)
  const int wc = w & 3;     // 0..3  (n quarter)
  const int quad = lane >> 4, l15 = lane & 15;

  // bijective XCD swizzle: 1024 blocks = 8 XCD * 128; per XCD: 32 m-tiles x 4 nc
  const int bid = blockIdx.x;
  const int sid = (bid & 7) * 128 + (bid >> 3);
  const int mt = sid >> 2;  // 0..255
  const int nc = sid & 3;   // 0..3
  const int m0 = mt * 256, n0 = nc * 256;

  // per-lane staging sources; source column pre-swizzled so linear LDS dest gets
  // phys col16 = (lane&7), holding logical col16 = (lane&7)^(row&7).
  const int r8 = lane >> 3, c8 = lane & 7;
  const int colel = (c8 ^ r8) * 8;
  // A quarter source: wave w covers rows q*64 + w*8 + r8; lane*16 = r8*128+c8*16.
  const char* aQ = (const char*)valh + ((size_t)(m0 + w * 8 + r8) * ND + colel) * 2;
  const char* bS[2];
#pragma unroll
  for (int i = 0; i < 2; ++i) {
    const int seg = w * 2 + i;
    bS[i] = (const char*)W1T + ((size_t)(n0 + seg * 8 + r8) * ND + colel) * 2;
  }
  const int aLw = w * 1024;   // A LDS: within-quarter wave base
  const int segL = w * 2048;  // B LDS seg base (i=0); i=1 adds 1024

#define STG_AQ(t, q, p)                                                               \
  glds16(aQ + (size_t)(q)*131072 + (size_t)(t)*128,                                   \
         lds + (p)*65536 + (q)*8192 + aLw)
#define STG_AP(t, qa, qb, p)                                                          \
  do {                                                                                \
    STG_AQ(t, qa, p);                                                                 \
    STG_AQ(t, qb, p);                                                                 \
  } while (0)
#define STG_BH(t, h, p)                                                               \
  do {                                                                                \
    glds16(bS[0] + (size_t)(h)*262144 + (size_t)(t)*128,                              \
           lds + (p)*65536 + 32768 + (h)*16384 + segL);                               \
    glds16(bS[1] + (size_t)(h)*262144 + (size_t)(t)*128,                              \
           lds + (p)*65536 + 32768 + (h)*16384 + segL + 1024);                        \
  } while (0)

  // fragment read offsets: row r byte = r*128; chunk ks*4+quad at pos ^(r&7)
  const int xr0 = ((quad + 0) ^ (l15 & 7)) * 16;
  const int xr1 = ((quad + 4) ^ (l15 & 7)) * 16;
  const int aRow = (wr * 128 + l15) * 128;         // + (mq*4+fm)*2048
  const int bRow = 32768 + (wc * 64 + l15) * 128;  // + fn*2048

  f16x8 af[4][2], bf[4][2];
  f32x4 acc[8][4];
#pragma unroll
  for (int i = 0; i < 8; ++i)
#pragma unroll
    for (int j = 0; j < 4; ++j) acc[i][j] = (f32x4){0.f, 0.f, 0.f, 0.f};

#define LDA(p, mq)                                                                    \
  do {                                                                                \
    _Pragma("unroll") for (int fm = 0; fm < 4; ++fm) {                                \
      const int rb = (p)*65536 + aRow + ((mq)*4 + fm) * 2048;                         \
      af[fm][0] = *(const f16x8*)(lds + rb + xr0);                                    \
      af[fm][1] = *(const f16x8*)(lds + rb + xr1);                                    \
    }                                                                                 \
  } while (0)
#define LDB(p)                                                                        \
  do {                                                                                \
    _Pragma("unroll") for (int fn = 0; fn < 4; ++fn) {                                \
      const int rb = (p)*65536 + bRow + fn * 2048;                                    \
      bf[fn][0] = *(const f16x8*)(lds + rb + xr0);                                    \
      bf[fn][1] = *(const f16x8*)(lds + rb + xr1);                                    \
    }                                                                                 \
  } while (0)
#define MM(mq, nq)                                                                    \
  do {                                                                                \
    _Pragma("unroll") for (int fm = 0; fm < 4; ++fm) {                                \
      _Pragma("unroll") for (int fn = 0; fn < 2; ++fn) {                              \
        acc[(mq)*4 + fm][(nq)*2 + fn] = __builtin_amdgcn_mfma_f32_16x16x32_f16(       \
            af[fm][0], bf[(nq)*2 + fn][0], acc[(mq)*4 + fm][(nq)*2 + fn], 0, 0, 0);   \
        acc[(mq)*4 + fm][(nq)*2 + fn] = __builtin_amdgcn_mfma_f32_16x16x32_f16(       \
            af[fm][1], bf[(nq)*2 + fn][1], acc[(mq)*4 + fm][(nq)*2 + fn], 0, 0, 0);   \
      }                                                                               \
    }                                                                                 \
  } while (0)
#define MIDBAR()                                                                      \
  do {                                                                                \
    __builtin_amdgcn_sched_barrier(0);                                                \
    __builtin_amdgcn_s_barrier();                                                     \
    asm volatile("s_waitcnt lgkmcnt(0)" ::: "memory");                                \
    __builtin_amdgcn_sched_barrier(0);                                                \
    __builtin_amdgcn_s_setprio(1);                                                    \
  } while (0)
#define ENDP()                                                                        \
  do {                                                                                \
    __builtin_amdgcn_s_setprio(0);                                                    \
    __builtin_amdgcn_sched_barrier(0);                                                \
    __builtin_amdgcn_s_barrier();                                                     \
  } while (0)
#define ENDPV()                                                                       \
  do {                                                                                \
    __builtin_amdgcn_s_setprio(0);                                                    \
    __builtin_amdgcn_sched_barrier(0);                                                \
    asm volatile("s_waitcnt vmcnt(4)" ::: "memory");                                  \
    __builtin_amdgcn_s_barrier();                                                     \
  } while (0)

  // prologue: A(0)->buf0, B(0)->buf0, A(1)->buf1; drain to leave A(1) in flight.
  STG_AP(0, 0, 2, 0);
  STG_AP(0, 1, 3, 0);
  STG_BH(0, 0, 0);
  STG_BH(0, 1, 0);
  STG_AP(1, 0, 2, 1);
  STG_AP(1, 1, 3, 1);
  asm volatile("s_waitcnt vmcnt(4)" ::: "memory");
  __builtin_amdgcn_s_barrier();

#define KTILE(p, tB, tA)                                                              \
  do {                                                                                \
    LDA(p, 0);                                                                        \
    LDB(p);                                                                           \
    STG_BH(tB, 0, (p) ^ 1);                                                           \
    MIDBAR();                                                                         \
    MM(0, 0);                                                                         \
    ENDP();                                                                           \
    STG_BH(tB, 1, (p) ^ 1);                                                           \
    MIDBAR();                                                                         \
    MM(0, 1);                                                                         \
    ENDP();                                                                           \
    LDA(p, 1);                                                                        \
    STG_AP(tA, 0, 2, p);                                                              \
    MIDBAR();                                                                         \
    MM(1, 0);                                                                         \
    ENDP();                                                                           \
    STG_AP(tA, 1, 3, p);                                                              \
    MIDBAR();                                                                         \
    MM(1, 1);                                                                         \
    ENDPV();                                                                          \
  } while (0)

  for (int I = 0; I < 8; ++I) {
    const int o = 2 * I + 1;
    const int t2 = (2 * I + 2 < 16) ? 2 * I + 2 : 15;
    const int t3 = (2 * I + 3 < 16) ? 2 * I + 3 : 15;
    KTILE(0, o, t2);   // even K-tile (buf0): stage B(o)->buf1, A(t2)->buf0
    KTILE(1, t2, t3);  // odd  K-tile (buf1): stage B(t2)->buf0, A(t3)->buf1
  }

  // epilogue: C/D layout col=lane&15, row=quad*4+reg (m89/m91-verified)
  const int b = m0 >> 11;
  float vv[4], qq[4];
#pragma unroll
  for (int ci = 0; ci < 4; ++ci) {
    const int col = n0 + wc * 64 + ci * 16 + l15;
    vv[ci] = V[col];
    qq[ci] = pq[b * NU + col];
  }
#pragma unroll
  for (int ri = 0; ri < 8; ++ri) {
    float p0 = 0.f, p1 = 0.f, p2 = 0.f, p3 = 0.f;
#pragma unroll
    for (int ci = 0; ci < 4; ++ci) {
      f32x4 a = acc[ri][ci];
      p0 += fast_tanh(a.x + qq[ci]) * vv[ci];
      p1 += fast_tanh(a.y + qq[ci]) * vv[ci];
      p2 += fast_tanh(a.z + qq[ci]) * vv[ci];
      p3 += fast_tanh(a.w + qq[ci]) * vv[ci];
    }
#pragma unroll
    for (int mask = 1; mask < 16; mask <<= 1) {
      p0 += __shfl_xor(p0, mask);
      p1 += __shfl_xor(p1, mask);
      p2 += __shfl_xor(p2, mask);
      p3 += __shfl_xor(p3, mask);
    }
    if (l15 == 0) {
      const int rbase = m0 + wr * 128 + ri * 16 + quad * 4;
      atomicAdd(&score[rbase + 0], p0);
      atomicAdd(&score[rbase + 1], p1);
      atomicAdd(&score[rbase + 2], p2);
      atomicAdd(&score[rbase + 3], p3);
    }
  }
#undef STG_AQ
#undef STG_AP
#undef STG_BH
#undef LDA
#undef LDB
#undef MM
#undef MIDBAR
#undef ENDP
#undef ENDPV
#undef KTILE
}

// ---------------- fallback: fused GEMM with fp32 A staging (R2 kernel) ----------
__global__ __launch_bounds__(256) void k_score_f32(const float* __restrict__ values,
                                                   const unsigned short* __restrict__ W1T,
                                                   const float* __restrict__ pq,
                                                   const float* __restrict__ V,
                                                   float* __restrict__ score) {
  __shared__ f32x4 lds4[1536];
  char* lds = (char*)lds4;
  const int tid = threadIdx.x;
  const int lane = tid & 63;
  const int w = tid >> 6;
  const int wr = w >> 1, wc = w & 1;
  const int quad = lane >> 4, l15 = lane & 15;
  const int bid = blockIdx.x;
  const int xcd = bid & 7;
  const int local = bid >> 3;
  const int mt = xcd * 64 + (local >> 3);
  const int nc = local & 7;
  const int m0 = mt * 128, n0 = nc * 128;
  const char* aG[4];
  uint32_t aL[4];
  {
    const int p = lane & 7, r3 = lane >> 3;
    const int ca = p ^ r3;
#pragma unroll
    for (int i = 0; i < 4; ++i) {
      const int seg = w * 4 + i;
      const int mloc = seg * 8 + r3;
      aG[i] = (const char*)values + (size_t)(m0 + mloc) * (ND * 4) + ca * 16;
      aL[i] = seg * 1024;
    }
  }
  const char* bG[2];
  uint32_t bL[2];
  {
    const int cb = (lane & 3) ^ ((lane >> 3) & 3);
#pragma unroll
    for (int i = 0; i < 2; ++i) {
      const int seg = w * 2 + i;
      const int nloc = seg * 16 + (lane >> 2);
      bG[i] = (const char*)W1T + (size_t)(n0 + nloc) * (ND * 2) + cb * 16;
      bL[i] = 16384 + seg * 1024;
    }
  }
  uint32_t aOff[4][2], bOff[4];
  {
    const int p0 = (2 * quad) ^ (l15 & 7);
#pragma unroll
    for (int ri = 0; ri < 4; ++ri) {
      const int m = wr * 64 + ri * 16 + l15;
      aOff[ri][0] = m * 128 + p0 * 16;
      aOff[ri][1] = m * 128 + (p0 ^ 1) * 16;
    }
    const int pb = quad ^ ((l15 >> 1) & 3);
#pragma unroll
    for (int ci = 0; ci < 4; ++ci) {
      const int n = wc * 64 + ci * 16 + l15;
      bOff[ci] = 16384 + n * 64 + pb * 16;
    }
  }
  f32x4 acc[4][4];
#pragma unroll
  for (int i = 0; i < 4; ++i)
#pragma unroll
    for (int j = 0; j < 4; ++j) acc[i][j] = (f32x4){0.f, 0.f, 0.f, 0.f};
  for (int kt = 0; kt < 32; ++kt) {
    __syncthreads();
    const size_t aCol = (size_t)kt * 128;
    const size_t bCol = (size_t)kt * 64;
#pragma unroll
    for (int i = 0; i < 4; ++i) glds16(aG[i] + aCol, lds + aL[i]);
#pragma unroll
    for (int i = 0; i < 2; ++i) glds16(bG[i] + bCol, lds + bL[i]);
    __syncthreads();
    bf16x8 af[4];
#pragma unroll
    for (int ri = 0; ri < 4; ++ri) {
      f32x4 v0 = *(const f32x4*)(lds + aOff[ri][0]);
      f32x4 v1 = *(const f32x4*)(lds + aOff[ri][1]);
      union { uint32_t u[4]; bf16x8 v; } cvt;
      cvt.u[0] = pack_bf16_trunc(v0.x, v0.y);
      cvt.u[1] = pack_bf16_trunc(v0.z, v0.w);
      cvt.u[2] = pack_bf16_trunc(v1.x, v1.y);
      cvt.u[3] = pack_bf16_trunc(v1.z, v1.w);
      af[ri] = cvt.v;
    }
    bf16x8 bfg[4];
#pragma unroll
    for (int ci = 0; ci < 4; ++ci) {
      union { f32x4 f; bf16x8 v; } u;
      u.f = *(const f32x4*)(lds + bOff[ci]);
      bfg[ci] = u.v;
    }
#pragma unroll
    for (int ri = 0; ri < 4; ++ri)
#pragma unroll
      for (int ci = 0; ci < 4; ++ci)
        acc[ri][ci] =
            __builtin_amdgcn_mfma_f32_16x16x32_bf16(af[ri], bfg[ci], acc[ri][ci], 0, 0, 0);
  }
  const int b = m0 >> 11;
  float vv[4], qq[4];
#pragma unroll
  for (int ci = 0; ci < 4; ++ci) {
    const int col = n0 + wc * 64 + ci * 16 + l15;
    vv[ci] = V[col];
    qq[ci] = pq[b * NU + col];
  }
#pragma unroll
  for (int ri = 0; ri < 4; ++ri) {
    float p0 = 0.f, p1 = 0.f, p2 = 0.f, p3 = 0.f;
#pragma unroll
    for (int ci = 0; ci < 4; ++ci) {
      f32x4 a = acc[ri][ci];
      p0 += fast_tanh(a.x + qq[ci]) * vv[ci];
      p1 += fast_tanh(a.y + qq[ci]) * vv[ci];
      p2 += fast_tanh(a.z + qq[ci]) * vv[ci];
      p3 += fast_tanh(a.w + qq[ci]) * vv[ci];
    }
#pragma unroll
    for (int mask = 1; mask < 16; mask <<= 1) {
      p0 += __shfl_xor(p0, mask);
      p1 += __shfl_xor(p1, mask);
      p2 += __shfl_xor(p2, mask);
      p3 += __shfl_xor(p3, mask);
    }
    if (l15 == 0) {
      const int rbase = m0 + wr * 64 + ri * 16 + quad * 4;
      atomicAdd(&score[rbase + 0], p0);
      atomicAdd(&score[rbase + 1], p1);
      atomicAdd(&score[rbase + 2], p2);
      atomicAdd(&score[rbase + 3], p3);
    }
  }
}

// ---------------- softmax over S per batch; writes attention output -------------
__global__ __launch_bounds__(256) void k_softmax(const float* __restrict__ score,
                                                 float* __restrict__ attn) {
  __shared__ float red[8];
  const int b = blockIdx.x, tid = threadIdx.x;
  const int w = tid >> 6, lane = tid & 63;
  const float* s = score + b * NS;
  float v[8];
  float mx = -3.4e38f;
#pragma unroll
  for (int j = 0; j < 8; ++j) {
    v[j] = s[tid + j * 256];
    mx = fmaxf(mx, v[j]);
  }
#pragma unroll
  for (int mask = 1; mask < 64; mask <<= 1) mx = fmaxf(mx, __shfl_xor(mx, mask));
  if (lane == 0) red[w] = mx;
  __syncthreads();
  mx = fmaxf(fmaxf(red[0], red[1]), fmaxf(red[2], red[3]));
  float sum = 0.f;
#pragma unroll
  for (int j = 0; j < 8; ++j) {
    v[j] = __expf(v[j] - mx);
    sum += v[j];
  }
#pragma unroll
  for (int mask = 1; mask < 64; mask <<= 1) sum += __shfl_xor(sum, mask);
  if (lane == 0) red[4 + w] = sum;
  __syncthreads();
  const float inv = 1.0f / (red[4] + red[5] + red[6] + red[7]);
  float* o = attn + b * NS;
#pragma unroll
  for (int j = 0; j < 8; ++j) o[tid + j * 256] = v[j] * inv;
}

// ---------------- context partials from fp16 values -----------------------------
__global__ __launch_bounds__(128) void k_ctx_part_h(const _Float16* __restrict__ valh,
                                                    const float* __restrict__ attn,
                                                    float* __restrict__ part) {
  const int sc = blockIdx.x, b = blockIdx.y, t = threadIdx.x;
  const int row0 = b * NS + sc * 32;
  const int d8 = t * 8;
  const float* ab = attn + row0;  // wave-uniform -> s_load
  float acc[8];
#pragma unroll
  for (int i = 0; i < 8; ++i) acc[i] = 0.f;
  for (int s0 = 0; s0 < 32; s0 += 8) {
    uint4 r[8];
#pragma unroll
    for (int j = 0; j < 8; ++j)
      r[j] = *(const uint4*)(valh + (size_t)(row0 + s0 + j) * ND + d8);
#pragma unroll
    for (int j = 0; j < 8; ++j) {
      union { uint4 u; _Float16 h[8]; } c;
      c.u = r[j];
      const float a = ab[s0 + j];
#pragma unroll
      for (int i = 0; i < 8; ++i) acc[i] = fmaf(a, (float)c.h[i], acc[i]);
    }
  }
  float* o = part + (size_t)(b * 64 + sc) * ND + d8;
#pragma unroll
  for (int i = 0; i < 8; ++i) o[i] = acc[i];
}

// ---------------- fallback fp32 context partials --------------------------------
__global__ __launch_bounds__(256) void k_ctx_part_f32(const float* __restrict__ values,
                                                      const float* __restrict__ attn,
                                                      float* __restrict__ part) {
  const int sc = blockIdx.x, b = blockIdx.y, tid = threadIdx.x;
  const int s0 = sc * 64;
  const f32x4* vb = (const f32x4*)(values + (size_t)(b * NS + s0) * ND);
  const float* ab = attn + b * NS + s0;
  f32x4 acc0 = (f32x4){0.f, 0.f, 0.f, 0.f};
  f32x4 acc1 = acc0;
  for (int s = 0; s < 64; s += 8) {
    f32x4 v0 = vb[(size_t)(s + 0) * 256 + tid];
    f32x4 v1 = vb[(size_t)(s + 1) * 256 + tid];
    f32x4 v2 = vb[(size_t)(s + 2) * 256 + tid];
    f32x4 v3 = vb[(size_t)(s + 3) * 256 + tid];
    f32x4 v4 = vb[(size_t)(s + 4) * 256 + tid];
    f32x4 v5 = vb[(size_t)(s + 5) * 256 + tid];
    f32x4 v6 = vb[(size_t)(s + 6) * 256 + tid];
    f32x4 v7 = vb[(size_t)(s + 7) * 256 + tid];
    acc0 += ab[s + 0] * v0;
    acc1 += ab[s + 1] * v1;
    acc0 += ab[s + 2] * v2;
    acc1 += ab[s + 3] * v3;
    acc0 += ab[s + 4] * v4;
    acc1 += ab[s + 5] * v5;
    acc0 += ab[s + 6] * v6;
    acc1 += ab[s + 7] * v7;
  }
  *(f32x4*)(part + (size_t)(b * 32 + sc) * ND + tid * 4) = acc0 + acc1;
}

__global__ __launch_bounds__(256) void k_ctx_red(const float* __restrict__ part,
                                                 float* __restrict__ ctx, int count) {
  const int b = blockIdx.x, tid = threadIdx.x;
  f32x4 acc = (f32x4){0.f, 0.f, 0.f, 0.f};
  for (int sc = 0; sc < count; ++sc)
    acc += *(const f32x4*)(part + (size_t)(b * count + sc) * ND + tid * 4);
  *(f32x4*)(ctx + (size_t)b * ND + tid * 4) = acc;
}

extern "C" void kernel_launch(void* const* d_in, const int* in_sizes, int n_in,
                              void* d_out, int out_size, void* d_ws, size_t ws_size,
                              hipStream_t stream) {
  const float* query  = (const float*)d_in[0];
  const float* values = (const float*)d_in[1];
  const float* W1     = (const float*)d_in[2];
  const float* b1     = (const float*)d_in[3];
  const float* W2     = (const float*)d_in[4];
  const float* b2     = (const float*)d_in[5];
  const float* V      = (const float*)d_in[6];
  // d_in[7] = bV: uniform score shift -> cancels in softmax.

  float* ctx  = (float*)d_out;
  float* attn = (float*)d_out + NB * ND;

  char* ws = (char*)d_ws;
  const size_t SZ_VALH = (size_t)NM * ND * 2;  // 128 MiB
  const size_t need_h = SZ_VALH + 2097152 + 524288 + 131072 + 262144 + 8388608;

  if (ws_size >= need_h) {
    _Float16* valh   = (_Float16*)ws;
    _Float16* W1Th   = (_Float16*)(ws + SZ_VALH);
    float* pq_part   = (float*)(ws + SZ_VALH + 2097152);
    float* pq        = (float*)(ws + SZ_VALH + 2621440);
    float* score     = (float*)(ws + SZ_VALH + 2752512);
    float* part      = (float*)(ws + SZ_VALH + 3014656);

    hipMemsetAsync(score, 0, NM * sizeof(float), stream);
    k_cvt<<<4096, 256, 0, stream>>>(values, valh);
    k_w1t_h<<<dim3(16, 16), 256, 0, stream>>>(W1, W1Th);
    k_pq<<<dim3(4, NB), 256, 0, stream>>>(query, W2, pq_part);
    k_pq_red<<<NB, 256, 0, stream>>>(pq_part, b1, b2, pq);
    k_score_h<<<1024, 512, 0, stream>>>(valh, W1Th, pq, V, score);
    k_softmax<<<NB, 256, 0, stream>>>(score, attn);
    k_ctx_part_h<<<dim3(64, NB), 128, 0, stream>>>(valh, attn, part);
    k_ctx_red<<<NB, 256, 0, stream>>>(part, ctx, 64);
  } else {
    unsigned short* W1T = (unsigned short*)ws;
    float* pq_part = (float*)(ws + 2097152);
    float* pq      = (float*)(ws + 2621440);
    float* score   = (float*)(ws + 2752512);
    float* part    = (float*)(ws + 3014656);

    hipMemsetAsync(score, 0, NM * sizeof(float), stream);
    k_w1t<<<dim3(16, 16), 256, 0, stream>>>(W1, W1T);
    k_pq<<<dim3(4, NB), 256, 0, stream>>>(query, W2, pq_part);
    k_pq_red<<<NB, 256, 0, stream>>>(pq_part, b1, b2, pq);
    k_score_f32<<<4096, 256, 0, stream>>>(values, W1T, pq, V, score);
    k_softmax<<<NB, 256, 0, stream>>>(score, attn);
    k_ctx_part_f32<<<dim3(32, NB), 256, 0, stream>>>(values, attn, part);
    k_ctx_red<<<NB, 256, 0, stream>>>(part, ctx, 32);
  }
}